// Round 8
// baseline (1978.589 us; speedup 1.0000x reference)
//
#include <hip/hip_runtime.h>
#include <hip/hip_bf16.h>

#define Bb 8
#define Tt 48
#define HZ 24
#define Nn 1024
#define Hh 512
#define NHEAD 8

typedef short short8 __attribute__((ext_vector_type(8)));
typedef float f32x4 __attribute__((ext_vector_type(4)));

__device__ __forceinline__ ushort f2bf(float f) {
  uint u = __builtin_bit_cast(uint, f);
  u += 0x7FFFu + ((u >> 16) & 1u);
  return (ushort)(u >> 16);
}

// ---- prep: repack Wv into per-lane MFMA fragment order ----
// W2[ch][w][kb][f=ki*2+nn][lane][e]  (ushort), 512KB total.
__global__ void wvt2_kernel(const float* __restrict__ Wv, ushort* __restrict__ W2) {
  int t = blockIdx.x * 256 + threadIdx.x;    // [0, 262144)
  int e = t & 7;
  int lane = (t >> 3) & 63;
  int f = (t >> 9) & 3;
  int kb = (t >> 11) & 7;
  int w = (t >> 14) & 3;
  int ch = t >> 16;
  int ki = f >> 1, nn = f & 1;
  int row = ch * 128 + w * 32 + nn * 16 + (lane & 15);
  int col = kb * 64 + ki * 32 + ((lane >> 4) << 3) + e;
  W2[t] = f2bf(Wv[col * 512 + row]);
}

// ---- prep: attention weights (fp32 softmax) -> bf16 padded [B][8][32][64] ----
__global__ void attn_kernel(const float* __restrict__ xt, const float* __restrict__ tt,
                            const float* __restrict__ Wq, const float* __restrict__ bq,
                            const float* __restrict__ Wk, const float* __restrict__ bk,
                            ushort* __restrict__ attnp) {
  __shared__ float qs[24][65];
  __shared__ float ks_[48][65];
  __shared__ float sc[24][49];
  int bh = blockIdx.x;                       // 64 blocks
  int b = bh >> 3, h = bh & 7;
  int t = threadIdx.x;
  for (int e = t; e < 24 * 64; e += 256) {
    int i = e >> 6, dd = e & 63;
    float s = bq[h * 64 + dd];
    const float* r = tt + (b * 24 + i) * 64;
    #pragma unroll 8
    for (int c = 0; c < 64; ++c) s += r[c] * Wq[c * 512 + h * 64 + dd];
    qs[i][dd] = s;
  }
  for (int e = t; e < 48 * 64; e += 256) {
    int j = e >> 6, dd = e & 63;
    float s = bk[h * 64 + dd];
    const float* r = xt + (b * 48 + j) * 64;
    #pragma unroll 8
    for (int c = 0; c < 64; ++c) s += r[c] * Wk[c * 512 + h * 64 + dd];
    ks_[j][dd] = s;
  }
  __syncthreads();
  for (int e = t; e < 24 * 48; e += 256) {
    int i = e / 48, j = e - i * 48;
    float s = 0.f;
    #pragma unroll 8
    for (int dd = 0; dd < 64; ++dd) s += qs[i][dd] * ks_[j][dd];
    sc[i][j] = s * 0.125f;                   // / sqrt(64)
  }
  __syncthreads();
  if (t < 32) {
    int i = t;
    ushort* orow = attnp + ((size_t)bh * 32 + i) * 64;
    if (i < 24) {
      float mx = -1e30f;
      for (int j = 0; j < 48; ++j) mx = fmaxf(mx, sc[i][j]);
      float sum = 0.f;
      for (int j = 0; j < 48; ++j) { float e = expf(sc[i][j] - mx); sc[i][j] = e; sum += e; }
      float inv = 1.f / sum;
      for (int j = 0; j < 48; ++j) orow[j] = f2bf(sc[i][j] * inv);
      for (int j = 48; j < 64; ++j) orow[j] = 0;
    } else {
      for (int j = 0; j < 64; ++j) orow[j] = 0;
    }
  }
}

// ---- main fused kernel ----
// kb OUTER, ch inner, acc[4][3][2] resident. A staged as a 3-slot ROTATING
// slice buffer (3 x [48][64] bf16 = 18KB) at distance 2; V^T per-wave 4KB
// (16KB). LDS total 34KB -> 4 blocks/CU (16 waves) with launch_bounds(256,4).
#define SLOT_SZ 6144
#define V_BASE 18432

__global__ __launch_bounds__(256, 4) void main_kernel(
    const float* __restrict__ EH, const ushort* __restrict__ W2,
    const ushort* __restrict__ attnp, const float* __restrict__ bv,
    float* __restrict__ out) {
  __shared__ __align__(128) char smem[34816];
  int bid = blockIdx.x;
  int b = bid >> 10, n = bid & 1023;
  int t = threadIdx.x;
  int lane = t & 63, w = t >> 6;
  int rowl = lane & 15;
  int colb = (lane >> 4) << 3;
  char* vbuf = smem + V_BASE + w * 4096;     // wave-private V^T scratch

  // hoist bv: bvr[ch][nn]
  float bvr[4][2];
  #pragma unroll
  for (int c = 0; c < 4; ++c)
    #pragma unroll
    for (int nn = 0; nn < 2; ++nn)
      bvr[c][nn] = bv[c * 128 + w * 32 + nn * 16 + rowl];

  // zero V^T pad cols 48..63 once (wave-private)
  {
    int lr = lane >> 1;
    int off = (lr << 7) + ((96 + ((lane & 1) << 4)) ^ ((lr & 7) << 4));
    *(uint4*)(vbuf + off) = make_uint4(0, 0, 0, 0);
  }

  const float* ehb = EH + (((size_t)b * Tt) * Nn + n) * Hh;
  int sj = t >> 4, sc4 = t & 15;             // staging map: rows sj+16i, col4 sc4

  // prologue: stage slices kb=0,1 into slots 0,1
  #pragma unroll
  for (int s = 0; s < 2; ++s) {
    #pragma unroll
    for (int i = 0; i < 3; ++i) {
      int j = sj + i * 16;
      float4 v = *(const float4*)(ehb + (size_t)j * (Nn * Hh) + (s * 16 + sc4) * 4);
      uint2 p;
      p.x = (uint)f2bf(v.x) | ((uint)f2bf(v.y) << 16);
      p.y = (uint)f2bf(v.z) | ((uint)f2bf(v.w) << 16);
      int off = s * SLOT_SZ + ((j << 7) + (sc4 << 3)) ^ ((j & 7) << 4);
      off = s * SLOT_SZ + (((j << 7) + (sc4 << 3)) ^ ((j & 7) << 4));
      *(uint2*)(smem + off) = p;
    }
  }
  __syncthreads();

  f32x4 acc[4][3][2] = {};                   // 96 VGPR accumulators
  #pragma unroll
  for (int kb = 0; kb < 8; ++kb) {
    const int slot = kb % 3;
    const int wslot = (kb + 2) % 3;
    // 1) issue global loads for slice kb+2 (in flight across MFMA phase)
    float4 ldv[3];
    if (kb < 6) {
      #pragma unroll
      for (int i = 0; i < 3; ++i) {
        int j = sj + i * 16;
        ldv[i] = *(const float4*)(ehb + (size_t)j * (Nn * Hh) + ((kb + 2) * 16 + sc4) * 4);
      }
    }
    // 2) A fragments for this kb (shared across ch): 6 ds_read_b128
    short8 af[2][3];
    #pragma unroll
    for (int ki = 0; ki < 2; ++ki) {
      int kc = ki * 32 + colb;               // local col within slice
      #pragma unroll
      for (int m = 0; m < 3; ++m) {
        int j = m * 16 + rowl;
        int off = slot * SLOT_SZ + (((j << 7) + (kc << 1)) ^ ((j & 7) << 4));
        af[ki][m] = *(const short8*)(smem + off);
      }
    }
    // 3) per-ch B fragments (coalesced L2 streams) + 12 MFMA each
    #pragma unroll
    for (int ch = 0; ch < 4; ++ch) {
      const ushort* wpf = W2 + (size_t)(ch * 4 + w) * 16384 + kb * 2048 + lane * 8;
      short8 bf0 = *(const short8*)(wpf);
      short8 bf1 = *(const short8*)(wpf + 512);
      short8 bf2 = *(const short8*)(wpf + 1024);
      short8 bf3 = *(const short8*)(wpf + 1536);
      #pragma unroll
      for (int m = 0; m < 3; ++m) {
        acc[ch][m][0] = __builtin_amdgcn_mfma_f32_16x16x32_bf16(af[0][m], bf0, acc[ch][m][0], 0, 0, 0);
        acc[ch][m][1] = __builtin_amdgcn_mfma_f32_16x16x32_bf16(af[0][m], bf1, acc[ch][m][1], 0, 0, 0);
      }
      #pragma unroll
      for (int m = 0; m < 3; ++m) {
        acc[ch][m][0] = __builtin_amdgcn_mfma_f32_16x16x32_bf16(af[1][m], bf2, acc[ch][m][0], 0, 0, 0);
        acc[ch][m][1] = __builtin_amdgcn_mfma_f32_16x16x32_bf16(af[1][m], bf3, acc[ch][m][1], 0, 0, 0);
      }
    }
    // 4) convert + ds_write slice kb+2 into its slot (distinct from slot, slot+1)
    if (kb < 6) {
      #pragma unroll
      for (int i = 0; i < 3; ++i) {
        int j = sj + i * 16;
        uint2 p;
        p.x = (uint)f2bf(ldv[i].x) | ((uint)f2bf(ldv[i].y) << 16);
        p.y = (uint)f2bf(ldv[i].z) | ((uint)f2bf(ldv[i].w) << 16);
        int off = wslot * SLOT_SZ + (((j << 7) + (sc4 << 3)) ^ ((j & 7) << 4));
        *(uint2*)(smem + off) = p;
      }
    }
    __syncthreads();
  }

  // ---- stage 2: per ch, V^T -> LDS (wave-private) then attn @ V ----
  #pragma unroll
  for (int ch = 0; ch < 4; ++ch) {
    int h = 2 * ch + (w >> 1);
    short8 pa[2][2];                         // [ks][itl]
    #pragma unroll
    for (int ks = 0; ks < 2; ++ks)
      #pragma unroll
      for (int itl = 0; itl < 2; ++itl) {
        int i = itl * 16 + rowl;
        pa[ks][itl] = *(const short8*)(attnp + (((size_t)(b * 8 + h) * 32 + i) * 64) + ks * 32 + colb);
      }

    // acc[ch] -> V^T bf16 (wave-private, swizzled)
    #pragma unroll
    for (int m = 0; m < 3; ++m) {
      #pragma unroll
      for (int nn = 0; nn < 2; ++nn) {
        int lr = nn * 16 + rowl;
        int j0 = m * 16 + ((lane >> 4) << 2);
        uint2 p;
        p.x = (uint)f2bf(acc[ch][m][nn][0]) | ((uint)f2bf(acc[ch][m][nn][1]) << 16);
        p.y = (uint)f2bf(acc[ch][m][nn][2]) | ((uint)f2bf(acc[ch][m][nn][3]) << 16);
        int off = (lr << 7) + ((j0 << 1) ^ ((lr & 7) << 4));
        *(uint2*)(vbuf + off) = p;
      }
    }
    asm volatile("s_waitcnt lgkmcnt(0)" ::: "memory");  // V writes done (same-wave reads next)
    __builtin_amdgcn_sched_barrier(0);

    f32x4 x[2][2] = {};
    #pragma unroll
    for (int ks = 0; ks < 2; ++ks) {
      short8 vb[2];
      #pragma unroll
      for (int nn = 0; nn < 2; ++nn) {
        int lr = nn * 16 + rowl;
        int off = (lr << 7) + (((ks * 32 + colb) << 1) ^ ((lr & 7) << 4));
        vb[nn] = *(const short8*)(vbuf + off);
      }
      #pragma unroll
      for (int itl = 0; itl < 2; ++itl)
        #pragma unroll
        for (int nn = 0; nn < 2; ++nn)
          x[itl][nn] = __builtin_amdgcn_mfma_f32_16x16x32_bf16(pa[ks][itl], vb[nn], x[itl][nn], 0, 0, 0);
    }
    asm volatile("s_waitcnt lgkmcnt(0)" ::: "memory");  // V reads done before next ch's writes
    __builtin_amdgcn_sched_barrier(0);

    // store X rows i<24 (+bv)
    #pragma unroll
    for (int itl = 0; itl < 2; ++itl) {
      int ib = itl * 16 + ((lane >> 4) << 2);
      #pragma unroll
      for (int nn = 0; nn < 2; ++nn) {
        int hd = ch * 128 + w * 32 + nn * 16 + rowl;
        float bvv = bvr[ch][nn];
        #pragma unroll
        for (int r = 0; r < 4; ++r) {
          int i = ib + r;
          if (i < 24)
            out[(((size_t)b * HZ + i) * Nn + n) * Hh + hd] = x[itl][nn][r] + bvv;
        }
      }
    }
  }
}

extern "C" void kernel_launch(void* const* d_in, const int* in_sizes, int n_in,
                              void* d_out, int out_size, void* d_ws, size_t ws_size,
                              hipStream_t stream) {
  (void)in_sizes; (void)n_in; (void)out_size; (void)ws_size;
  const float* EH = (const float*)d_in[0];
  const float* xt = (const float*)d_in[1];
  const float* tt = (const float*)d_in[2];
  const float* Wq = (const float*)d_in[3];
  const float* bq = (const float*)d_in[4];
  const float* Wk = (const float*)d_in[5];
  const float* bk = (const float*)d_in[6];
  const float* Wv = (const float*)d_in[7];
  const float* bv = (const float*)d_in[8];
  float* out = (float*)d_out;
  ushort* W2 = (ushort*)d_ws;                                    // 512 KB
  ushort* attnp = (ushort*)((char*)d_ws + 512 * 1024);           // 256 KB

  wvt2_kernel<<<1024, 256, 0, stream>>>(Wv, W2);
  attn_kernel<<<64, 256, 0, stream>>>(xt, tt, Wq, bq, Wk, bk, attnp);
  main_kernel<<<8192, 256, 0, stream>>>(EH, W2, attnp, bv, out);
}

// Round 9
// 484.529 us; speedup vs baseline: 4.0835x; 4.0835x over previous
//
#include <hip/hip_runtime.h>
#include <hip/hip_bf16.h>

#define Bb 8
#define Tt 48
#define HZ 24
#define Nn 1024
#define Hh 512
#define NHEAD 8

typedef short short8 __attribute__((ext_vector_type(8)));
typedef short bf16x4 __attribute__((ext_vector_type(4)));
typedef float f32x4 __attribute__((ext_vector_type(4)));

__device__ __forceinline__ ushort f2bf(float f) {
  uint u = __builtin_bit_cast(uint, f);
  u += 0x7FFFu + ((u >> 16) & 1u);
  return (ushort)(u >> 16);
}

// K=16 bf16 MFMA: D[i=g*4+reg][hd=l&15] += sum_{k=g*4+e} A[l&15][k]*B[l&15][k]
__device__ __forceinline__ f32x4 mfma16(bf16x4 a, bf16x4 b, f32x4 c) {
#if __has_builtin(__builtin_amdgcn_mfma_f32_16x16x16bf16_1k)
  return __builtin_amdgcn_mfma_f32_16x16x16bf16_1k(a, b, c, 0, 0, 0);
#elif __has_builtin(__builtin_amdgcn_mfma_f32_16x16x16_bf16)
  return __builtin_amdgcn_mfma_f32_16x16x16_bf16(a, b, c, 0, 0, 0);
#else
  f32x4 d;
  asm volatile("v_mfma_f32_16x16x16_bf16 %0, %1, %2, %3\n\ts_nop 7\n\ts_nop 4"
               : "=v"(d) : "v"(a), "v"(b), "v"(c));
  return d;
#endif
}

// ---- prep: repack Wv into per-lane MFMA fragment order ----
// W2[ch][w][kb][f=ki*2+nn][lane][e]  (ushort), 512KB total.
__global__ void wvt2_kernel(const float* __restrict__ Wv, ushort* __restrict__ W2) {
  int t = blockIdx.x * 256 + threadIdx.x;    // [0, 262144)
  int e = t & 7;
  int lane = (t >> 3) & 63;
  int f = (t >> 9) & 3;
  int kb = (t >> 11) & 7;
  int w = (t >> 14) & 3;
  int ch = t >> 16;
  int ki = f >> 1, nn = f & 1;
  int row = ch * 128 + w * 32 + nn * 16 + (lane & 15);
  int col = kb * 64 + ki * 32 + ((lane >> 4) << 3) + e;
  W2[t] = f2bf(Wv[col * 512 + row]);
}

// ---- prep: attention weights (fp32 softmax) -> bf16 padded [B][8][32][64] ----
__global__ void attn_kernel(const float* __restrict__ xt, const float* __restrict__ tt,
                            const float* __restrict__ Wq, const float* __restrict__ bq,
                            const float* __restrict__ Wk, const float* __restrict__ bk,
                            ushort* __restrict__ attnp) {
  __shared__ float qs[24][65];
  __shared__ float ks_[48][65];
  __shared__ float sc[24][49];
  int bh = blockIdx.x;                       // 64 blocks
  int b = bh >> 3, h = bh & 7;
  int t = threadIdx.x;
  for (int e = t; e < 24 * 64; e += 256) {
    int i = e >> 6, dd = e & 63;
    float s = bq[h * 64 + dd];
    const float* r = tt + (b * 24 + i) * 64;
    #pragma unroll 8
    for (int c = 0; c < 64; ++c) s += r[c] * Wq[c * 512 + h * 64 + dd];
    qs[i][dd] = s;
  }
  for (int e = t; e < 48 * 64; e += 256) {
    int j = e >> 6, dd = e & 63;
    float s = bk[h * 64 + dd];
    const float* r = xt + (b * 48 + j) * 64;
    #pragma unroll 8
    for (int c = 0; c < 64; ++c) s += r[c] * Wk[c * 512 + h * 64 + dd];
    ks_[j][dd] = s;
  }
  __syncthreads();
  for (int e = t; e < 24 * 48; e += 256) {
    int i = e / 48, j = e - i * 48;
    float s = 0.f;
    #pragma unroll 8
    for (int dd = 0; dd < 64; ++dd) s += qs[i][dd] * ks_[j][dd];
    sc[i][j] = s * 0.125f;                   // / sqrt(64)
  }
  __syncthreads();
  if (t < 32) {
    int i = t;
    ushort* orow = attnp + ((size_t)bh * 32 + i) * 64;
    if (i < 24) {
      float mx = -1e30f;
      for (int j = 0; j < 48; ++j) mx = fmaxf(mx, sc[i][j]);
      float sum = 0.f;
      for (int j = 0; j < 48; ++j) { float e = expf(sc[i][j] - mx); sc[i][j] = e; sum += e; }
      float inv = 1.f / sum;
      for (int j = 0; j < 48; ++j) orow[j] = f2bf(sc[i][j] * inv);
      for (int j = 48; j < 64; ++j) orow[j] = 0;
    } else {
      for (int j = 0; j < 64; ++j) orow[j] = 0;
    }
  }
}

// ---- main fused kernel ----
// LDS: A[48][512] bf16 swizzled = 48KB ONLY -> 3 blocks/CU (12 waves).
// B fragments in registers (coalesced W2 streams, 1-deep prefetch).
// Stage-2 is register-only: the stage-1 acc C-layout IS the K=16 MFMA
// B-fragment layout (lane holds V[j=g*4+reg][hd=nn*16+(l&15)]), so
// X = attn @ V runs as 12 mfma_16x16x16 per ch with zero data movement.
#define A_BASE 0

__global__ __launch_bounds__(256, 3) void main_kernel(
    const float* __restrict__ EH, const ushort* __restrict__ W2,
    const ushort* __restrict__ attnp, const float* __restrict__ bv,
    float* __restrict__ out) {
  __shared__ __align__(128) char smem[49152];
  int bid = blockIdx.x;
  int b = bid >> 10, n = bid & 1023;
  int t = threadIdx.x;
  int lane = t & 63, w = t >> 6;
  int rowl = lane & 15;
  int colb = (lane >> 4) << 3;               // K=32 fragment k-offset (elements)
  int colb16 = (lane >> 4) << 2;             // K=16 fragment k-offset (elements)

  // hoist bv: bvr[ch][nn]
  float bvr[4][2];
  #pragma unroll
  for (int c = 0; c < 4; ++c)
    #pragma unroll
    for (int nn = 0; nn < 2; ++nn)
      bvr[c][nn] = bv[c * 128 + w * 32 + nn * 16 + rowl];

  // B fragment stream base for this wave (per (ch,w): 16384 ushorts = 32KB;
  // per-ch stride = 65536 ushorts)
  const ushort* wp0 = W2 + (size_t)w * 16384 + lane * 8;

  // prologue: prefetch (ch=0, kb=0) fragments
  short8 bc[4], bn[4];
  #pragma unroll
  for (int f = 0; f < 4; ++f) bc[f] = *(const short8*)(wp0 + f * 512);

  // stage A: EH[b][j][n][0..511] fp32 -> bf16 LDS (swizzle ^((j&7)<<4))
  {
    const float* ehb = EH + (((size_t)b * Tt) * Nn + n) * Hh;
    #pragma unroll 8
    for (int it = 0; it < 24; ++it) {
      int f = it * 256 + t;                  // 48 rows * 128 float4
      int j = f >> 7, c4 = f & 127;
      float4 v = *(const float4*)(ehb + (size_t)j * (Nn * Hh) + c4 * 4);
      uint2 p;
      p.x = (uint)f2bf(v.x) | ((uint)f2bf(v.y) << 16);
      p.y = (uint)f2bf(v.z) | ((uint)f2bf(v.w) << 16);
      int off = (j << 10) + (c4 << 3);
      off ^= (j & 7) << 4;
      *(uint2*)(smem + A_BASE + off) = p;
    }
  }
  __syncthreads();   // the ONLY barrier: A visible to all waves

  #pragma unroll
  for (int ch = 0; ch < 4; ++ch) {
    const ushort* wp = W2 + (size_t)(ch * 4 + w) * 16384 + lane * 8;
    f32x4 acc[3][2] = {};
    #pragma unroll
    for (int kb = 0; kb < 8; ++kb) {
      // 1-deep register prefetch (crosses the ch boundary; next ch = +65536)
      if (kb < 7) {
        #pragma unroll
        for (int f = 0; f < 4; ++f)
          bn[f] = *(const short8*)(wp + (kb + 1) * 2048 + f * 512);
      } else if (ch < 3) {
        #pragma unroll
        for (int f = 0; f < 4; ++f)
          bn[f] = *(const short8*)(wp + 65536 + f * 512);
      }
      #pragma unroll
      for (int ki = 0; ki < 2; ++ki) {
        short8 af[3];
        int kc = kb * 64 + ki * 32 + colb;
        #pragma unroll
        for (int m = 0; m < 3; ++m) {
          int j = m * 16 + rowl;
          int off = (j << 10) + (kc << 1);
          off ^= (j & 7) << 4;
          af[m] = *(const short8*)(smem + A_BASE + off);
        }
        #pragma unroll
        for (int m = 0; m < 3; ++m) {
          acc[m][0] = __builtin_amdgcn_mfma_f32_16x16x32_bf16(af[m], bc[ki * 2 + 0], acc[m][0], 0, 0, 0);
          acc[m][1] = __builtin_amdgcn_mfma_f32_16x16x32_bf16(af[m], bc[ki * 2 + 1], acc[m][1], 0, 0, 0);
        }
      }
      #pragma unroll
      for (int f = 0; f < 4; ++f) bc[f] = bn[f];
    }

    // ---- stage 2 (register-only): X[i,hd] = sum_j attn[h,i,j] * V[j,hd] ----
    // acc[m][nn] in lane l holds V[j=m*16+g*4+reg][hd=nn*16+(l&15)], which is
    // exactly the K=16 MFMA B-fragment for k-chunk j in [m*16, m*16+16).
    int h = 2 * ch + (w >> 1);
    const ushort* arow = attnp + ((size_t)(b * 8 + h) * 32) * 64;
    f32x4 x[2][2] = {};
    #pragma unroll
    for (int m = 0; m < 3; ++m) {
      bf16x4 pa[2];
      #pragma unroll
      for (int itl = 0; itl < 2; ++itl)
        pa[itl] = *(const bf16x4*)(arow + (itl * 16 + rowl) * 64 + m * 16 + colb16);
      #pragma unroll
      for (int nn = 0; nn < 2; ++nn) {
        bf16x4 vbq;
        vbq[0] = (short)f2bf(acc[m][nn][0]);
        vbq[1] = (short)f2bf(acc[m][nn][1]);
        vbq[2] = (short)f2bf(acc[m][nn][2]);
        vbq[3] = (short)f2bf(acc[m][nn][3]);
        x[0][nn] = mfma16(pa[0], vbq, x[0][nn]);
        x[1][nn] = mfma16(pa[1], vbq, x[1][nn]);
      }
    }

    // store X rows i<24 (+bv; softmax rows sum to 1 so bias passes through)
    #pragma unroll
    for (int itl = 0; itl < 2; ++itl) {
      int ib = itl * 16 + ((lane >> 4) << 2);
      #pragma unroll
      for (int nn = 0; nn < 2; ++nn) {
        int hd = ch * 128 + w * 32 + nn * 16 + rowl;
        float bvv = bvr[ch][nn];
        #pragma unroll
        for (int r = 0; r < 4; ++r) {
          int i = ib + r;
          if (i < 24)
            out[(((size_t)b * HZ + i) * Nn + n) * Hh + hd] = x[itl][nn][r] + bvv;
        }
      }
    }
  }
}

extern "C" void kernel_launch(void* const* d_in, const int* in_sizes, int n_in,
                              void* d_out, int out_size, void* d_ws, size_t ws_size,
                              hipStream_t stream) {
  (void)in_sizes; (void)n_in; (void)out_size; (void)ws_size;
  const float* EH = (const float*)d_in[0];
  const float* xt = (const float*)d_in[1];
  const float* tt = (const float*)d_in[2];
  const float* Wq = (const float*)d_in[3];
  const float* bq = (const float*)d_in[4];
  const float* Wk = (const float*)d_in[5];
  const float* bk = (const float*)d_in[6];
  const float* Wv = (const float*)d_in[7];
  const float* bv = (const float*)d_in[8];
  float* out = (float*)d_out;
  ushort* W2 = (ushort*)d_ws;                                    // 512 KB
  ushort* attnp = (ushort*)((char*)d_ws + 512 * 1024);           // 256 KB

  wvt2_kernel<<<1024, 256, 0, stream>>>(Wv, W2);
  attn_kernel<<<64, 256, 0, stream>>>(xt, tt, Wq, bq, Wk, bk, attnp);
  main_kernel<<<8192, 256, 0, stream>>>(EH, W2, attnp, bv, out);
}

// Round 10
// 471.429 us; speedup vs baseline: 4.1970x; 1.0278x over previous
//
#include <hip/hip_runtime.h>
#include <hip/hip_bf16.h>

#define Bb 8
#define Tt 48
#define HZ 24
#define Nn 1024
#define Hh 512
#define NHEAD 8

typedef short short8 __attribute__((ext_vector_type(8)));
typedef short bf16x4 __attribute__((ext_vector_type(4)));
typedef float f32x4 __attribute__((ext_vector_type(4)));

__device__ __forceinline__ ushort f2bf(float f) {
  uint u = __builtin_bit_cast(uint, f);
  u += 0x7FFFu + ((u >> 16) & 1u);
  return (ushort)(u >> 16);
}

// K=16 bf16 MFMA: lane l holds B[k=g*4+reg][col=l&15]; acc C-layout matches.
__device__ __forceinline__ f32x4 mfma16(bf16x4 a, bf16x4 b, f32x4 c) {
#if __has_builtin(__builtin_amdgcn_mfma_f32_16x16x16bf16_1k)
  return __builtin_amdgcn_mfma_f32_16x16x16bf16_1k(a, b, c, 0, 0, 0);
#elif __has_builtin(__builtin_amdgcn_mfma_f32_16x16x16_bf16)
  return __builtin_amdgcn_mfma_f32_16x16x16_bf16(a, b, c, 0, 0, 0);
#else
  f32x4 d;
  asm volatile("v_mfma_f32_16x16x16_bf16 %0, %1, %2, %3\n\ts_nop 7\n\ts_nop 4"
               : "=v"(d) : "v"(a), "v"(b), "v"(c));
  return d;
#endif
}

// ---- prep: repack Wv into per-lane MFMA fragment order ----
// W2[ch][w][kb][f=ki*2+nn][lane][e]  (ushort), 512KB total.
__global__ void wvt2_kernel(const float* __restrict__ Wv, ushort* __restrict__ W2) {
  int t = blockIdx.x * 256 + threadIdx.x;    // [0, 262144)
  int e = t & 7;
  int lane = (t >> 3) & 63;
  int f = (t >> 9) & 3;
  int kb = (t >> 11) & 7;
  int w = (t >> 14) & 3;
  int ch = t >> 16;
  int ki = f >> 1, nn = f & 1;
  int row = ch * 128 + w * 32 + nn * 16 + (lane & 15);
  int col = kb * 64 + ki * 32 + ((lane >> 4) << 3) + e;
  W2[t] = f2bf(Wv[col * 512 + row]);
}

// ---- prep: attention weights (fp32 softmax) -> bf16 padded [B][8][32][64] ----
__global__ void attn_kernel(const float* __restrict__ xt, const float* __restrict__ tt,
                            const float* __restrict__ Wq, const float* __restrict__ bq,
                            const float* __restrict__ Wk, const float* __restrict__ bk,
                            ushort* __restrict__ attnp) {
  __shared__ float qs[24][65];
  __shared__ float ks_[48][65];
  __shared__ float sc[24][49];
  int bh = blockIdx.x;                       // 64 blocks
  int b = bh >> 3, h = bh & 7;
  int t = threadIdx.x;
  for (int e = t; e < 24 * 64; e += 256) {
    int i = e >> 6, dd = e & 63;
    float s = bq[h * 64 + dd];
    const float* r = tt + (b * 24 + i) * 64;
    #pragma unroll 8
    for (int c = 0; c < 64; ++c) s += r[c] * Wq[c * 512 + h * 64 + dd];
    qs[i][dd] = s;
  }
  for (int e = t; e < 48 * 64; e += 256) {
    int j = e >> 6, dd = e & 63;
    float s = bk[h * 64 + dd];
    const float* r = xt + (b * 48 + j) * 64;
    #pragma unroll 8
    for (int c = 0; c < 64; ++c) s += r[c] * Wk[c * 512 + h * 64 + dd];
    ks_[j][dd] = s;
  }
  __syncthreads();
  for (int e = t; e < 24 * 48; e += 256) {
    int i = e / 48, j = e - i * 48;
    float s = 0.f;
    #pragma unroll 8
    for (int dd = 0; dd < 64; ++dd) s += qs[i][dd] * ks_[j][dd];
    sc[i][j] = s * 0.125f;                   // / sqrt(64)
  }
  __syncthreads();
  if (t < 32) {
    int i = t;
    ushort* orow = attnp + ((size_t)bh * 32 + i) * 64;
    if (i < 24) {
      float mx = -1e30f;
      for (int j = 0; j < 48; ++j) mx = fmaxf(mx, sc[i][j]);
      float sum = 0.f;
      for (int j = 0; j < 48; ++j) { float e = expf(sc[i][j] - mx); sc[i][j] = e; sum += e; }
      float inv = 1.f / sum;
      for (int j = 0; j < 48; ++j) orow[j] = f2bf(sc[i][j] * inv);
      for (int j = 48; j < 64; ++j) orow[j] = 0;
    } else {
      for (int j = 0; j < 64; ++j) orow[j] = 0;
    }
  }
}

// ---- main fused kernel ----
// LDS: A[48][512] bf16 swizzled = 48KB only. B fragments in registers from
// repacked W2 (coalesced 1KB/load), 2-DEEP prefetch in a flat unrolled
// ck=(ch,kb) loop. Stage-2 register-only (acc C-layout == K=16 B-fragment).
// ONE __syncthreads per block; setprio around MFMA clusters (T5).
#define A_BASE 0

__global__ __launch_bounds__(256, 2) void main_kernel(
    const float* __restrict__ EH, const ushort* __restrict__ W2,
    const ushort* __restrict__ attnp, const float* __restrict__ bv,
    float* __restrict__ out) {
  __shared__ __align__(128) char smem[49152];
  int bid = blockIdx.x;
  int b = bid >> 10, n = bid & 1023;
  int t = threadIdx.x;
  int lane = t & 63, w = t >> 6;
  int rowl = lane & 15;
  int colb = (lane >> 4) << 3;               // K=32 fragment k-offset (elements)
  int colb16 = (lane >> 4) << 2;             // K=16 fragment k-offset (elements)

  // hoist bv: bvr[ch][nn]
  float bvr[4][2];
  #pragma unroll
  for (int c = 0; c < 4; ++c)
    #pragma unroll
    for (int nn = 0; nn < 2; ++nn)
      bvr[c][nn] = bv[c * 128 + w * 32 + nn * 16 + rowl];

  // per-(ch,w) W2 panel: 16384 ushorts; per-kb: 2048; frag: 512
  const ushort* wbase = W2 + (size_t)w * 16384 + lane * 8;

  // prologue: prefetch ck=0 and ck=1 (ch0/kb0, ch0/kb1) — fly during A-stage
  short8 b0[4], b1[4];
  #pragma unroll
  for (int f = 0; f < 4; ++f) b0[f] = *(const short8*)(wbase + f * 512);
  #pragma unroll
  for (int f = 0; f < 4; ++f) b1[f] = *(const short8*)(wbase + 2048 + f * 512);

  // stage A: EH[b][j][n][0..511] fp32 -> bf16 LDS (swizzle ^((j&7)<<4))
  {
    const float* ehb = EH + (((size_t)b * Tt) * Nn + n) * Hh;
    #pragma unroll 8
    for (int it = 0; it < 24; ++it) {
      int f = it * 256 + t;                  // 48 rows * 128 float4
      int j = f >> 7, c4 = f & 127;
      float4 v = *(const float4*)(ehb + (size_t)j * (Nn * Hh) + c4 * 4);
      uint2 p;
      p.x = (uint)f2bf(v.x) | ((uint)f2bf(v.y) << 16);
      p.y = (uint)f2bf(v.z) | ((uint)f2bf(v.w) << 16);
      int off = (j << 10) + (c4 << 3);
      off ^= (j & 7) << 4;
      *(uint2*)(smem + A_BASE + off) = p;
    }
  }
  __syncthreads();   // the ONLY barrier: A visible to all waves

  f32x4 acc[3][2] = {};
  #pragma unroll
  for (int ck = 0; ck < 32; ++ck) {
    const int kb = ck & 7;
    // 2-deep prefetch: issue loads for ck+2 (all indices compile-time)
    short8 bnext[4];
    if (ck < 30) {
      const int ck2 = ck + 2;
      const ushort* wp2 = wbase + (size_t)((ck2 >> 3) * 4) * 16384 + (ck2 & 7) * 2048;
      #pragma unroll
      for (int f = 0; f < 4; ++f) bnext[f] = *(const short8*)(wp2 + f * 512);
    }
    // A fragments for this kb: 6 ds_read_b128
    short8 af[2][3];
    #pragma unroll
    for (int ki = 0; ki < 2; ++ki) {
      int kc = kb * 64 + ki * 32 + colb;
      #pragma unroll
      for (int m = 0; m < 3; ++m) {
        int j = m * 16 + rowl;
        int off = (j << 10) + (kc << 1);
        off ^= (j & 7) << 4;
        af[ki][m] = *(const short8*)(smem + A_BASE + off);
      }
    }
    // 12 MFMA on b0 (current), wrapped in setprio
    __builtin_amdgcn_s_setprio(1);
    #pragma unroll
    for (int m = 0; m < 3; ++m) {
      acc[m][0] = __builtin_amdgcn_mfma_f32_16x16x32_bf16(af[0][m], b0[0], acc[m][0], 0, 0, 0);
      acc[m][1] = __builtin_amdgcn_mfma_f32_16x16x32_bf16(af[0][m], b0[1], acc[m][1], 0, 0, 0);
    }
    #pragma unroll
    for (int m = 0; m < 3; ++m) {
      acc[m][0] = __builtin_amdgcn_mfma_f32_16x16x32_bf16(af[1][m], b0[2], acc[m][0], 0, 0, 0);
      acc[m][1] = __builtin_amdgcn_mfma_f32_16x16x32_bf16(af[1][m], b0[3], acc[m][1], 0, 0, 0);
    }
    __builtin_amdgcn_s_setprio(0);
    // rotate (SSA renaming under full unroll; no real moves)
    #pragma unroll
    for (int f = 0; f < 4; ++f) b0[f] = b1[f];
    if (ck < 30) {
      #pragma unroll
      for (int f = 0; f < 4; ++f) b1[f] = bnext[f];
    }

    // end of a ch: stage-2 (register-only) + store, then reset acc
    if (kb == 7) {
      const int ch = ck >> 3;
      int h = 2 * ch + (w >> 1);
      const ushort* arow = attnp + ((size_t)(b * 8 + h) * 32) * 64;
      f32x4 x[2][2] = {};
      #pragma unroll
      for (int m = 0; m < 3; ++m) {
        bf16x4 pa[2];
        #pragma unroll
        for (int itl = 0; itl < 2; ++itl)
          pa[itl] = *(const bf16x4*)(arow + (itl * 16 + rowl) * 64 + m * 16 + colb16);
        #pragma unroll
        for (int nn = 0; nn < 2; ++nn) {
          bf16x4 vbq;
          vbq[0] = (short)f2bf(acc[m][nn][0]);
          vbq[1] = (short)f2bf(acc[m][nn][1]);
          vbq[2] = (short)f2bf(acc[m][nn][2]);
          vbq[3] = (short)f2bf(acc[m][nn][3]);
          x[0][nn] = mfma16(pa[0], vbq, x[0][nn]);
          x[1][nn] = mfma16(pa[1], vbq, x[1][nn]);
        }
      }
      #pragma unroll
      for (int itl = 0; itl < 2; ++itl) {
        int ib = itl * 16 + ((lane >> 4) << 2);
        #pragma unroll
        for (int nn = 0; nn < 2; ++nn) {
          int hd = ch * 128 + w * 32 + nn * 16 + rowl;
          float bvv = bvr[ch][nn];
          #pragma unroll
          for (int r = 0; r < 4; ++r) {
            int i = ib + r;
            if (i < 24)
              out[(((size_t)b * HZ + i) * Nn + n) * Hh + hd] = x[itl][nn][r] + bvv;
          }
        }
      }
      #pragma unroll
      for (int m = 0; m < 3; ++m)
        #pragma unroll
        for (int nn = 0; nn < 2; ++nn)
          acc[m][nn] = f32x4{0.f, 0.f, 0.f, 0.f};
    }
  }
}

extern "C" void kernel_launch(void* const* d_in, const int* in_sizes, int n_in,
                              void* d_out, int out_size, void* d_ws, size_t ws_size,
                              hipStream_t stream) {
  (void)in_sizes; (void)n_in; (void)out_size; (void)ws_size;
  const float* EH = (const float*)d_in[0];
  const float* xt = (const float*)d_in[1];
  const float* tt = (const float*)d_in[2];
  const float* Wq = (const float*)d_in[3];
  const float* bq = (const float*)d_in[4];
  const float* Wk = (const float*)d_in[5];
  const float* bk = (const float*)d_in[6];
  const float* Wv = (const float*)d_in[7];
  const float* bv = (const float*)d_in[8];
  float* out = (float*)d_out;
  ushort* W2 = (ushort*)d_ws;                                    // 512 KB
  ushort* attnp = (ushort*)((char*)d_ws + 512 * 1024);           // 256 KB

  wvt2_kernel<<<1024, 256, 0, stream>>>(Wv, W2);
  attn_kernel<<<64, 256, 0, stream>>>(xt, tt, Wq, bq, Wk, bk, attnp);
  main_kernel<<<8192, 256, 0, stream>>>(EH, W2, attnp, bv, out);
}